// Round 13
// baseline (10796.310 us; speedup 1.0000x reference)
//
#include <hip/hip_runtime.h>
#include <math.h>

#define SEQ   2048
#define HID   2048
#define NHEAD 16
#define HD    128

// ---------------------------------------------------------------------------
// Naive f32 GEMM (NN):  C[M][N] = A[M][K] * B[K][N] + bias[N].  f32 out.
// 64x64 tile, 256 threads (16x16), 4x4 micro-tile, BK=16, f32 LDS.
// ---------------------------------------------------------------------------
__global__ __launch_bounds__(256) void gemm_nn(const float* __restrict__ A,
                                               const float* __restrict__ B,
                                               const float* __restrict__ bias,
                                               float* __restrict__ Cf,
                                               int M, int N, int K) {
  __shared__ float As[64][17];
  __shared__ float Bs[16][65];
  const int t = threadIdx.x;
  const int tx = t & 15, ty = t >> 4;
  const int m0 = blockIdx.x * 64, n0 = blockIdx.y * 64;
  float acc[4][4] = {};

  for (int k0 = 0; k0 < K; k0 += 16) {
    __syncthreads();
    {
      int arow = t >> 2, ac = (t & 3) * 4;
      const float* ap = &A[(size_t)(m0 + arow) * K + k0 + ac];
      As[arow][ac] = ap[0]; As[arow][ac + 1] = ap[1];
      As[arow][ac + 2] = ap[2]; As[arow][ac + 3] = ap[3];
      int brow = t >> 4, bc = (t & 15) * 4;
      const float* bp = &B[(size_t)(k0 + brow) * N + n0 + bc];
      Bs[brow][bc] = bp[0]; Bs[brow][bc + 1] = bp[1];
      Bs[brow][bc + 2] = bp[2]; Bs[brow][bc + 3] = bp[3];
    }
    __syncthreads();
#pragma unroll
    for (int kk = 0; kk < 16; ++kk) {
      float ar[4], br[4];
#pragma unroll
      for (int i = 0; i < 4; ++i) ar[i] = As[ty * 4 + i][kk];
#pragma unroll
      for (int j = 0; j < 4; ++j) br[j] = Bs[kk][tx * 4 + j];
#pragma unroll
      for (int i = 0; i < 4; ++i)
#pragma unroll
        for (int j = 0; j < 4; ++j) acc[i][j] += ar[i] * br[j];
    }
  }

#pragma unroll
  for (int i = 0; i < 4; ++i)
#pragma unroll
    for (int j = 0; j < 4; ++j) {
      int m = m0 + ty * 4 + i, n = n0 + tx * 4 + j;
      Cf[(size_t)m * N + n] = acc[i][j] + bias[n];
    }
}

// ---------------------------------------------------------------------------
// RMSNorm(q,k over full 2048) + interleaved RoPE + head-major relayout, f32.
// Split-into-thirds qkv packing.  Q pre-scaled 1/sqrt(D).  Qh/Kh: [h][s][d].
// (r5 baseline, unchanged)
// ---------------------------------------------------------------------------
__global__ __launch_bounds__(256) void rmsrope_f32(const float* __restrict__ fcos,
                                                   const float* __restrict__ fsin,
                                                   const float* __restrict__ qkv,
                                                   const float* __restrict__ wq,
                                                   const float* __restrict__ wk,
                                                   float* __restrict__ Qh,
                                                   float* __restrict__ Kh) {
  const int s = blockIdx.x, t = threadIdx.x;
  const float* row = qkv + (size_t)s * (3 * HID);
  __shared__ float red[256];

  float sq = 0.f, sk = 0.f;
#pragma unroll
  for (int j = 0; j < 8; ++j) {
    float a = row[t * 8 + j];       sq += a * a;
    float b = row[HID + t * 8 + j]; sk += b * b;
  }
  red[t] = sq;
  __syncthreads();
  for (int o = 128; o > 0; o >>= 1) {
    if (t < o) red[t] += red[t + o];
    __syncthreads();
  }
  const float rq = rsqrtf(red[0] / (float)HID + 1e-6f);
  __syncthreads();
  red[t] = sk;
  __syncthreads();
  for (int o = 128; o > 0; o >>= 1) {
    if (t < o) red[t] += red[t + o];
    __syncthreads();
  }
  const float rk = rsqrtf(red[0] / (float)HID + 1e-6f);

  const float qscale = 0.08838834764831845f;  // 1/sqrt(128)
#pragma unroll
  for (int p = 0; p < 4; ++p) {
    int c = t * 8 + p * 2;
    int h = c >> 7;
    int d = c & 127;
    int pi = d >> 1;
    float co = fcos[(size_t)s * (HD / 2) + pi];
    float si = fsin[(size_t)s * (HD / 2) + pi];
    float q1 = row[c] * rq * wq[c];
    float q2 = row[c + 1] * rq * wq[c + 1];
    float k1 = row[HID + c] * rk * wk[c];
    float k2 = row[HID + c + 1] * rk * wk[c + 1];
    size_t o = ((size_t)h * SEQ + s) * HD + d;
    Qh[o]     = (q1 * co - q2 * si) * qscale;
    Qh[o + 1] = (q1 * si + q2 * co) * qscale;
    Kh[o]     = k1 * co - k2 * si;
    Kh[o + 1] = k1 * si + k2 * co;
  }
}

// ---------------------------------------------------------------------------
// Two-pass softmax attention, f32 (r5 baseline).  One block per (q, head).
// V read in place from qkv slice 2.  Standard (B,S,HID) merge.
// ---------------------------------------------------------------------------
__global__ __launch_bounds__(256) void attn_f32(const float* __restrict__ Qh,
                                                const float* __restrict__ Kh,
                                                const float* __restrict__ qkv,
                                                float* __restrict__ attnO) {
  const int q = blockIdx.x, h = blockIdx.y, t = threadIdx.x;
  __shared__ float P[SEQ];
  __shared__ float qs[HD];
  __shared__ float red[256];
  const float* Kb = Kh + (size_t)h * SEQ * HD;
  const float* Vb = qkv + 2 * HID + h * HD;  // V[kv][d] = Vb[kv*3*HID + d]

  if (t < HD) qs[t] = Qh[((size_t)h * SEQ + q) * HD + t];
  __syncthreads();

  float lmax = -1e30f;
#pragma unroll
  for (int it = 0; it < 8; ++it) {
    int kv = it * 256 + t;
    const float* kr = &Kb[(size_t)kv * HD];
    float sc = 0.f;
    for (int d = 0; d < HD; ++d) sc += qs[d] * kr[d];
    P[kv] = sc;
    lmax = fmaxf(lmax, sc);
  }
  red[t] = lmax;
  __syncthreads();
  for (int o = 128; o > 0; o >>= 1) {
    if (t < o) red[t] = fmaxf(red[t], red[t + o]);
    __syncthreads();
  }
  const float m = red[0];
  __syncthreads();

  float lsum = 0.f;
#pragma unroll
  for (int it = 0; it < 8; ++it) {
    int kv = it * 256 + t;
    float p = expf(P[kv] - m);
    P[kv] = p;
    lsum += p;
  }
  red[t] = lsum;
  __syncthreads();
  for (int o = 128; o > 0; o >>= 1) {
    if (t < o) red[t] += red[t + o];
    __syncthreads();
  }
  const float inv = 1.0f / red[0];

  if (t < HD) {
    float o = 0.f;
    for (int kv = 0; kv < SEQ; ++kv)
      o += P[kv] * Vb[(size_t)kv * (3 * HID) + t];
    attnO[(size_t)q * HID + h * HD + t] = o * inv;
  }
}

// ---------------------------------------------------------------------------
extern "C" void kernel_launch(void* const* d_in, const int* in_sizes, int n_in,
                              void* d_out, int out_size, void* d_ws, size_t ws_size,
                              hipStream_t stream) {
  (void)in_sizes; (void)n_in; (void)out_size; (void)ws_size;
  const float* hs   = (const float*)d_in[0];
  const float* fc   = (const float*)d_in[1];
  const float* fs   = (const float*)d_in[2];
  const float* wqkv = (const float*)d_in[3];
  const float* bqkv = (const float*)d_in[4];
  const float* wnq  = (const float*)d_in[5];
  const float* wnk  = (const float*)d_in[6];
  const float* wout = (const float*)d_in[7];
  const float* bout = (const float*)d_in[8];
  float* out = (float*)d_out;   // *** f32 OUTPUT — the fix ***
  char* ws = (char*)d_ws;

  float* qkvF  = (float*)(ws);              // 2048x6144 f32 (50,331,648 B)
  float* QhF   = (float*)(ws + 50331648);   // 16x2048x128 f32
  float* KhF   = (float*)(ws + 67108864);   // 16x2048x128 f32
  float* attnF = (float*)(ws + 83886080);   // 2048x2048 f32 -> end 100,663,296

  // 1) QKV GEMM (f32, native (K,N) layout)
  gemm_nn<<<dim3(32, 96), 256, 0, stream>>>(hs, wqkv, bqkv, qkvF,
                                            SEQ, 3 * HID, HID);
  // 2) RMSNorm + interleaved RoPE, split-thirds packing
  rmsrope_f32<<<dim3(SEQ), 256, 0, stream>>>(fc, fs, qkvF, wnq, wnk, QhF, KhF);
  // 3) attention (f32 two-pass)
  attn_f32<<<dim3(SEQ, NHEAD), 256, 0, stream>>>(QhF, KhF, qkvF, attnF);
  // 4) output projection -> d_out (FLOAT32)
  gemm_nn<<<dim3(32, 32), 256, 0, stream>>>(attnF, wout, bout, out,
                                            SEQ, HID, HID);
}

// Round 14
// 372.230 us; speedup vs baseline: 29.0044x; 29.0044x over previous
//
#include <hip/hip_runtime.h>
#include <math.h>

typedef unsigned short u16;
typedef __bf16 bf16x8 __attribute__((ext_vector_type(8)));
typedef float f32x4 __attribute__((ext_vector_type(4)));
typedef unsigned short u16x8 __attribute__((ext_vector_type(8)));

#define SLEN 2048
#define HIDN 2048
#define NH   16
#define DHD  128

static __device__ __forceinline__ float bf2f(u16 u) {
  unsigned int i = ((unsigned int)u) << 16;
  return __builtin_bit_cast(float, i);
}
static __device__ __forceinline__ u16 f2bf(float f) {
  unsigned int x = __builtin_bit_cast(unsigned int, f);
  unsigned int r = x + 0x7fffu + ((x >> 16) & 1u);
  return (u16)(r >> 16);
}
static __device__ __forceinline__ void gload_lds16(const u16* g, u16* l) {
  __builtin_amdgcn_global_load_lds((const __attribute__((address_space(1))) void*)g,
                                   (__attribute__((address_space(3))) void*)l,
                                   16, 0, 0);
}

// ---------------------------------------------------------------------------
// Transpose + convert f32 -> bf16:  out[c][r] = (bf16)in[r][c].  64x64 tiles.
// ---------------------------------------------------------------------------
__global__ __launch_bounds__(256) void transpcvt(const float* __restrict__ in,
                                                 u16* __restrict__ out,
                                                 int istride, int ostride) {
  __shared__ float tl[64][65];
  const int t = threadIdx.x;
  const int r0 = blockIdx.x * 64, c0 = blockIdx.y * 64;
#pragma unroll
  for (int it = 0; it < 4; ++it) {
    int row = it * 16 + (t >> 4);
    int col = (t & 15) * 4;
    f32x4 v = *(const f32x4*)&in[(size_t)(r0 + row) * istride + c0 + col];
    tl[row][col] = v[0]; tl[row][col + 1] = v[1];
    tl[row][col + 2] = v[2]; tl[row][col + 3] = v[3];
  }
  __syncthreads();
#pragma unroll
  for (int it = 0; it < 2; ++it) {
    int orow = it * 32 + (t >> 3);
    int ocol = (t & 7) * 8;
    u16x8 v;
#pragma unroll
    for (int j = 0; j < 8; ++j) v[j] = f2bf(tl[ocol + j][orow]);
    *(u16x8*)&out[(size_t)(c0 + orow) * ostride + r0 + ocol] = v;
  }
}

// ---------------------------------------------------------------------------
// Elementwise f32 -> bf16 convert.
// ---------------------------------------------------------------------------
__global__ __launch_bounds__(256) void cvt_bf16(const float* __restrict__ in,
                                                u16* __restrict__ out) {
  int i = (blockIdx.x * 256 + threadIdx.x) * 8;
  f32x4 a = *(const f32x4*)&in[i];
  f32x4 b = *(const f32x4*)&in[i + 4];
  u16x8 v;
#pragma unroll
  for (int j = 0; j < 4; ++j) { v[j] = f2bf(a[j]); v[4 + j] = f2bf(b[j]); }
  *(u16x8*)&out[i] = v;
}

// ---------------------------------------------------------------------------
// bf16 tile transpose: out[c][r] = in[r][c].  64x64 tiles, grid (R/64,C/64,Z).
// ---------------------------------------------------------------------------
__global__ __launch_bounds__(256) void transp(const u16* __restrict__ in,
                                              u16* __restrict__ out,
                                              int istride, int ostride,
                                              int in_z, int out_z) {
  in  += (size_t)blockIdx.z * in_z;
  out += (size_t)blockIdx.z * out_z;
  __shared__ u16 tl[64][72];
  const int t  = threadIdx.x;
  const int r0 = blockIdx.x * 64, c0 = blockIdx.y * 64;
#pragma unroll
  for (int it = 0; it < 2; ++it) {
    int row = it * 32 + (t >> 3);
    int col = (t & 7) * 8;
    *(u16x8*)&tl[row][col] =
        *(const u16x8*)&in[(size_t)(r0 + row) * istride + c0 + col];
  }
  __syncthreads();
#pragma unroll
  for (int it = 0; it < 2; ++it) {
    int orow = it * 32 + (t >> 3);
    int ocol = (t & 7) * 8;
    u16x8 v;
#pragma unroll
    for (int j = 0; j < 8; ++j) v[j] = tl[ocol + j][orow];
    *(u16x8*)&out[(size_t)(c0 + orow) * ostride + r0 + ocol] = v;
  }
}

// ---------------------------------------------------------------------------
// MFMA GEMM  C[M][N] = A[M][K] * BT[N][K]^T + bias(f32).  bf16 in, f32 accum.
// 128x128 tile, BK=64, 4 waves (2x2 of 64x64), mfma_f32_16x16x32_bf16,
// XOR-swizzled LDS + pre-swizzled global source for global_load_lds.
// Writes f32 (Cf) or bf16 (Cb).   [validated r2-r4]
// ---------------------------------------------------------------------------
__global__ __launch_bounds__(256) void gemm_bt(const u16* __restrict__ A,
                                               const u16* __restrict__ BT,
                                               const float* __restrict__ bias,
                                               float* Cf, u16* Cb,
                                               int M, int N, int K) {
  __shared__ u16 lA[128 * 64];
  __shared__ u16 lB[128 * 64];
  const int t = threadIdx.x;
  const int lane = t & 63, w = t >> 6;
  const int g = lane >> 4, l16 = lane & 15;
  const int wr = w >> 1, wc = w & 1;
  const u16* Ab = A + (size_t)blockIdx.x * 128 * K;
  const u16* Bb = BT + (size_t)blockIdx.y * 128 * K;

  f32x4 acc[4][4];
#pragma unroll
  for (int mi = 0; mi < 4; ++mi)
#pragma unroll
    for (int ni = 0; ni < 4; ++ni) acc[mi][ni] = (f32x4)(0.0f);

  for (int k0 = 0; k0 < K; k0 += 64) {
    __syncthreads();
#pragma unroll
    for (int i = 0; i < 4; ++i) {
      int e = t * 8 + i * 2048;
      int row = e >> 6;
      int col16 = (e & 63) >> 3;
      int scol = (col16 ^ (row & 7)) * 8;
      gload_lds16(Ab + (size_t)row * K + k0 + scol, &lA[e]);
      gload_lds16(Bb + (size_t)row * K + k0 + scol, &lB[e]);
    }
    __syncthreads();
#pragma unroll
    for (int kk = 0; kk < 2; ++kk) {
      bf16x8 af[4], bfr[4];
#pragma unroll
      for (int mi = 0; mi < 4; ++mi) {
        int row = wr * 64 + mi * 16 + l16;
        af[mi] = *(const bf16x8*)&lA[row * 64 + (((4 * kk + g) ^ (l16 & 7)) << 3)];
      }
#pragma unroll
      for (int ni = 0; ni < 4; ++ni) {
        int row = wc * 64 + ni * 16 + l16;
        bfr[ni] = *(const bf16x8*)&lB[row * 64 + (((4 * kk + g) ^ (l16 & 7)) << 3)];
      }
#pragma unroll
      for (int mi = 0; mi < 4; ++mi)
#pragma unroll
        for (int ni = 0; ni < 4; ++ni)
          acc[mi][ni] = __builtin_amdgcn_mfma_f32_16x16x32_bf16(af[mi], bfr[ni],
                                                                acc[mi][ni], 0, 0, 0);
    }
  }

#pragma unroll
  for (int ni = 0; ni < 4; ++ni) {
    int n = blockIdx.y * 128 + wc * 64 + ni * 16 + l16;
    float bv = bias[n];
#pragma unroll
    for (int mi = 0; mi < 4; ++mi) {
      int m = blockIdx.x * 128 + wr * 64 + mi * 16 + 4 * g;
#pragma unroll
      for (int r = 0; r < 4; ++r) {
        float v = acc[mi][ni][r] + bv;
        if (Cf) Cf[(size_t)(m + r) * N + n] = v;
        else    Cb[(size_t)(m + r) * N + n] = f2bf(v);
      }
    }
  }
}

// ---------------------------------------------------------------------------
// Per-token RMSNorm(q,k) + interleaved RoPE + head-major relayout.
// bf16 qkv in, f32 freqs/weights, bf16 out.  Q pre-scaled 1/sqrt(D).
// [validated r2-r4]
// ---------------------------------------------------------------------------
__global__ __launch_bounds__(256) void rms_rope(const u16* __restrict__ qkv,
                                                const float* __restrict__ fcos,
                                                const float* __restrict__ fsin,
                                                const float* __restrict__ wq,
                                                const float* __restrict__ wk,
                                                u16* __restrict__ Qr,
                                                u16* __restrict__ Kr) {
  const int s = blockIdx.x;
  const int t = threadIdx.x;
  const int lane = t & 63, w = t >> 6;
  __shared__ float red[2][4];
  const u16* row = qkv + (size_t)s * (3 * HIDN);

  u16x8 xq = *(const u16x8*)&row[t * 8];
  u16x8 xk = *(const u16x8*)&row[HIDN + t * 8];
  float fq[8], fk[8];
  float ssq = 0.f, ssk = 0.f;
#pragma unroll
  for (int j = 0; j < 8; ++j) {
    fq[j] = bf2f(xq[j]); ssq += fq[j] * fq[j];
    fk[j] = bf2f(xk[j]); ssk += fk[j] * fk[j];
  }
#pragma unroll
  for (int off = 32; off >= 1; off >>= 1) {
    ssq += __shfl_xor(ssq, off);
    ssk += __shfl_xor(ssk, off);
  }
  if (lane == 0) { red[0][w] = ssq; red[1][w] = ssk; }
  __syncthreads();
  float sq = red[0][0] + red[0][1] + red[0][2] + red[0][3];
  float sk = red[1][0] + red[1][1] + red[1][2] + red[1][3];
  float rq = rsqrtf(sq / (float)HIDN + 1e-6f);
  float rk = rsqrtf(sk / (float)HIDN + 1e-6f);

  f32x4 wq0 = *(const f32x4*)&wq[t * 8];
  f32x4 wq1 = *(const f32x4*)&wq[t * 8 + 4];
  f32x4 wk0 = *(const f32x4*)&wk[t * 8];
  f32x4 wk1 = *(const f32x4*)&wk[t * 8 + 4];
  float wqa[8] = {wq0[0], wq0[1], wq0[2], wq0[3], wq1[0], wq1[1], wq1[2], wq1[3]};
  float wka[8] = {wk0[0], wk0[1], wk0[2], wk0[3], wk1[0], wk1[1], wk1[2], wk1[3]};
  const int c0 = t * 8;
  const int h = c0 >> 7;
  const int d0 = c0 & 127;
  const int i0 = d0 >> 1;
  const float* cp = fcos + (size_t)s * (DHD / 2) + i0;
  const float* sp = fsin + (size_t)s * (DHD / 2) + i0;
  const float qscale = 0.08838834764831845f;  // 1/sqrt(128)

  u16x8 oq, ok;
#pragma unroll
  for (int p = 0; p < 4; ++p) {
    float c = cp[p], sn = sp[p];
    float q1 = fq[2 * p] * rq * wqa[2 * p];
    float q2 = fq[2 * p + 1] * rq * wqa[2 * p + 1];
    float k1 = fk[2 * p] * rk * wka[2 * p];
    float k2 = fk[2 * p + 1] * rk * wka[2 * p + 1];
    oq[2 * p]     = f2bf((q1 * c - q2 * sn) * qscale);
    oq[2 * p + 1] = f2bf((q1 * sn + q2 * c) * qscale);
    ok[2 * p]     = f2bf(k1 * c - k2 * sn);
    ok[2 * p + 1] = f2bf(k1 * sn + k2 * c);
  }
  size_t o = (size_t)h * SLEN * DHD + (size_t)s * DHD + d0;
  *(u16x8*)&Qr[o] = oq;
  *(u16x8*)&Kr[o] = ok;
}

// ---------------------------------------------------------------------------
// MFMA flash attention.  grid (S/64, H), 4 waves, 16 q-rows/wave, KVBLK=64.
// K from Kr[h][s][d], V from Vt[h][d][s].  Online softmax, P via LDS.
// [validated r2-r4]
// ---------------------------------------------------------------------------
__global__ __launch_bounds__(256) void attn_fwd(const u16* __restrict__ Qr,
                                                const u16* __restrict__ Kr,
                                                const u16* __restrict__ Vt,
                                                u16* __restrict__ out) {
  const int h = blockIdx.y;
  const int t = threadIdx.x;
  const int lane = t & 63, w = t >> 6;
  const int g = lane >> 4, l16 = lane & 15;
  const int q0 = blockIdx.x * 64 + w * 16;
  const u16* Qh = Qr + (size_t)h * SLEN * DHD;
  const u16* Kh = Kr + (size_t)h * SLEN * DHD;
  const u16* Vh = Vt + (size_t)h * DHD * SLEN;

  __shared__ u16 Pl[4][16][72];

  bf16x8 aq[4];
#pragma unroll
  for (int dk = 0; dk < 4; ++dk)
    aq[dk] = *(const bf16x8*)&Qh[(size_t)(q0 + l16) * DHD + dk * 32 + g * 8];

  f32x4 o[8];
#pragma unroll
  for (int df = 0; df < 8; ++df) o[df] = (f32x4)(0.0f);
  float m[4], lsum[4];
#pragma unroll
  for (int r = 0; r < 4; ++r) { m[r] = -INFINITY; lsum[r] = 0.f; }

  for (int kt = 0; kt < SLEN / 64; ++kt) {
    const int kv0 = kt * 64;
    f32x4 s4[4];
#pragma unroll
    for (int nf = 0; nf < 4; ++nf) s4[nf] = (f32x4)(0.0f);
#pragma unroll
    for (int nf = 0; nf < 4; ++nf) {
#pragma unroll
      for (int dk = 0; dk < 4; ++dk) {
        bf16x8 bk = *(const bf16x8*)&Kh[(size_t)(kv0 + nf * 16 + l16) * DHD + dk * 32 + g * 8];
        s4[nf] = __builtin_amdgcn_mfma_f32_16x16x32_bf16(aq[dk], bk, s4[nf], 0, 0, 0);
      }
    }
    float tm[4];
#pragma unroll
    for (int r = 0; r < 4; ++r) {
      tm[r] = s4[0][r];
#pragma unroll
      for (int nf = 1; nf < 4; ++nf) tm[r] = fmaxf(tm[r], s4[nf][r]);
    }
#pragma unroll
    for (int off = 1; off < 16; off <<= 1)
#pragma unroll
      for (int r = 0; r < 4; ++r) tm[r] = fmaxf(tm[r], __shfl_xor(tm[r], off));
    float corr[4], ts[4];
#pragma unroll
    for (int r = 0; r < 4; ++r) {
      float mn = fmaxf(m[r], tm[r]);
      corr[r] = __expf(m[r] - mn);
      m[r] = mn;
      ts[r] = 0.f;
    }
#pragma unroll
    for (int nf = 0; nf < 4; ++nf)
#pragma unroll
      for (int r = 0; r < 4; ++r) {
        float p = __expf(s4[nf][r] - m[r]);
        s4[nf][r] = p;
        ts[r] += p;
      }
#pragma unroll
    for (int off = 1; off < 16; off <<= 1)
#pragma unroll
      for (int r = 0; r < 4; ++r) ts[r] += __shfl_xor(ts[r], off);
#pragma unroll
    for (int r = 0; r < 4; ++r) lsum[r] = lsum[r] * corr[r] + ts[r];
#pragma unroll
    for (int df = 0; df < 8; ++df)
#pragma unroll
      for (int r = 0; r < 4; ++r) o[df][r] *= corr[r];
#pragma unroll
    for (int nf = 0; nf < 4; ++nf)
#pragma unroll
      for (int r = 0; r < 4; ++r)
        Pl[w][4 * g + r][nf * 16 + l16] = f2bf(s4[nf][r]);
#pragma unroll
    for (int ks = 0; ks < 2; ++ks) {
      bf16x8 ap = *(const bf16x8*)&Pl[w][l16][ks * 32 + g * 8];
#pragma unroll
      for (int df = 0; df < 8; ++df) {
        bf16x8 bv = *(const bf16x8*)&Vh[(size_t)(df * 16 + l16) * SLEN + kv0 + ks * 32 + g * 8];
        o[df] = __builtin_amdgcn_mfma_f32_16x16x32_bf16(ap, bv, o[df], 0, 0, 0);
      }
    }
  }

  float inv[4];
#pragma unroll
  for (int r = 0; r < 4; ++r) inv[r] = 1.0f / lsum[r];
#pragma unroll
  for (int df = 0; df < 8; ++df)
#pragma unroll
    for (int r = 0; r < 4; ++r)
      out[(size_t)(q0 + 4 * g + r) * HIDN + h * DHD + df * 16 + l16] =
          f2bf(o[df][r] * inv[r]);
}

// ---------------------------------------------------------------------------
extern "C" void kernel_launch(void* const* d_in, const int* in_sizes, int n_in,
                              void* d_out, int out_size, void* d_ws, size_t ws_size,
                              hipStream_t stream) {
  (void)in_sizes; (void)n_in; (void)out_size; (void)ws_size;
  const float* hs   = (const float*)d_in[0];
  const float* fc   = (const float*)d_in[1];
  const float* fs   = (const float*)d_in[2];
  const float* wqkv = (const float*)d_in[3];
  const float* bqkv = (const float*)d_in[4];
  const float* wnq  = (const float*)d_in[5];
  const float* wnk  = (const float*)d_in[6];
  const float* wout = (const float*)d_in[7];
  const float* bout = (const float*)d_in[8];
  float* out = (float*)d_out;   // f32 output (r13 fix)
  char* ws = (char*)d_ws;

  u16* wqkvT = (u16*)(ws);                  // 6144x2048 bf16 (25,165,824 B)
  u16* woutT = (u16*)(ws + 25165824);       // 2048x2048 bf16 ( 8,388,608 B)
  u16* qkv   = (u16*)(ws + 33554432);       // 2048x6144 bf16 (25,165,824 B)
  u16* hsB   = (u16*)(ws + 58720256);       // 2048x2048 bf16
  u16* Qr    = (u16*)(ws + 58720256);       // alias hsB (dead after GEMM1)
  u16* Kr    = (u16*)(ws + 67108864);       // 16x2048x128 bf16
  u16* Vt    = (u16*)(ws + 75497472);       // 16x128x2048 bf16
  u16* attnO = (u16*)(ws + 83886080);       // 2048x2048 bf16 -> end 92,274,688

  // 1) weight transpose+convert, hidden convert (f32 -> bf16)
  transpcvt<<<dim3(32, 96), 256, 0, stream>>>(wqkv, wqkvT, 6144, 2048);
  transpcvt<<<dim3(32, 32), 256, 0, stream>>>(wout, woutT, 2048, 2048);
  cvt_bf16<<<dim3(2048), 256, 0, stream>>>(hs, hsB);
  // 2) QKV GEMM (MFMA)
  gemm_bt<<<dim3(16, 48), 256, 0, stream>>>(hsB, wqkvT, bqkv, nullptr, qkv,
                                            2048, 6144, 2048);
  // 3) RMSNorm + RoPE + head-major relayout (Q pre-scaled 1/sqrt(D))
  rms_rope<<<dim3(2048), 256, 0, stream>>>(qkv, fc, fs, wnq, wnk, Qr, Kr);
  // 4) V transpose -> Vt[h][d][s]
  transp<<<dim3(32, 2, 16), 256, 0, stream>>>(qkv + 4096, Vt, 6144, 2048, 128, 262144);
  // 5) MFMA flash attention
  attn_fwd<<<dim3(32, 16), 256, 0, stream>>>(Qr, Kr, Vt, attnO);
  // 6) output projection -> d_out (f32)
  gemm_bt<<<dim3(16, 16), 256, 0, stream>>>(attnO, woutT, bout, out, nullptr,
                                            2048, 2048, 2048);
}

// Round 15
// 229.549 us; speedup vs baseline: 47.0326x; 1.6216x over previous
//
#include <hip/hip_runtime.h>
#include <math.h>

typedef unsigned short u16;
typedef __bf16 bf16x8 __attribute__((ext_vector_type(8)));
typedef float f32x4 __attribute__((ext_vector_type(4)));
typedef unsigned short u16x8 __attribute__((ext_vector_type(8)));

#define SLEN 2048
#define HIDN 2048
#define NH   16
#define DHD  128

static __device__ __forceinline__ float bf2f(u16 u) {
  unsigned int i = ((unsigned int)u) << 16;
  return __builtin_bit_cast(float, i);
}
static __device__ __forceinline__ u16 f2bf(float f) {
  unsigned int x = __builtin_bit_cast(unsigned int, f);
  unsigned int r = x + 0x7fffu + ((x >> 16) & 1u);
  return (u16)(r >> 16);
}
static __device__ __forceinline__ void gload_lds16(const u16* g, u16* l) {
  __builtin_amdgcn_global_load_lds((const __attribute__((address_space(1))) void*)g,
                                   (__attribute__((address_space(3))) void*)l,
                                   16, 0, 0);
}

// ---------------------------------------------------------------------------
// Transpose + convert f32 -> bf16:  out[c][r] = (bf16)in[r][c].  64x64 tiles.
// ---------------------------------------------------------------------------
__global__ __launch_bounds__(256) void transpcvt(const float* __restrict__ in,
                                                 u16* __restrict__ out,
                                                 int istride, int ostride) {
  __shared__ float tl[64][65];
  const int t = threadIdx.x;
  const int r0 = blockIdx.x * 64, c0 = blockIdx.y * 64;
#pragma unroll
  for (int it = 0; it < 4; ++it) {
    int row = it * 16 + (t >> 4);
    int col = (t & 15) * 4;
    f32x4 v = *(const f32x4*)&in[(size_t)(r0 + row) * istride + c0 + col];
    tl[row][col] = v[0]; tl[row][col + 1] = v[1];
    tl[row][col + 2] = v[2]; tl[row][col + 3] = v[3];
  }
  __syncthreads();
#pragma unroll
  for (int it = 0; it < 2; ++it) {
    int orow = it * 32 + (t >> 3);
    int ocol = (t & 7) * 8;
    u16x8 v;
#pragma unroll
    for (int j = 0; j < 8; ++j) v[j] = f2bf(tl[ocol + j][orow]);
    *(u16x8*)&out[(size_t)(c0 + orow) * ostride + r0 + ocol] = v;
  }
}

// ---------------------------------------------------------------------------
// Elementwise f32 -> bf16 convert.
// ---------------------------------------------------------------------------
__global__ __launch_bounds__(256) void cvt_bf16(const float* __restrict__ in,
                                                u16* __restrict__ out) {
  int i = (blockIdx.x * 256 + threadIdx.x) * 8;
  f32x4 a = *(const f32x4*)&in[i];
  f32x4 b = *(const f32x4*)&in[i + 4];
  u16x8 v;
#pragma unroll
  for (int j = 0; j < 4; ++j) { v[j] = f2bf(a[j]); v[4 + j] = f2bf(b[j]); }
  *(u16x8*)&out[i] = v;
}

// ---------------------------------------------------------------------------
// bf16 tile transpose: out[c][r] = in[r][c].  64x64 tiles, grid (R/64,C/64,Z).
// ---------------------------------------------------------------------------
__global__ __launch_bounds__(256) void transp(const u16* __restrict__ in,
                                              u16* __restrict__ out,
                                              int istride, int ostride,
                                              int in_z, int out_z) {
  in  += (size_t)blockIdx.z * in_z;
  out += (size_t)blockIdx.z * out_z;
  __shared__ u16 tl[64][72];
  const int t  = threadIdx.x;
  const int r0 = blockIdx.x * 64, c0 = blockIdx.y * 64;
#pragma unroll
  for (int it = 0; it < 2; ++it) {
    int row = it * 32 + (t >> 3);
    int col = (t & 7) * 8;
    *(u16x8*)&tl[row][col] =
        *(const u16x8*)&in[(size_t)(r0 + row) * istride + c0 + col];
  }
  __syncthreads();
#pragma unroll
  for (int it = 0; it < 2; ++it) {
    int orow = it * 32 + (t >> 3);
    int ocol = (t & 7) * 8;
    u16x8 v;
#pragma unroll
    for (int j = 0; j < 8; ++j) v[j] = tl[ocol + j][orow];
    *(u16x8*)&out[(size_t)(c0 + orow) * ostride + r0 + ocol] = v;
  }
}

// ---------------------------------------------------------------------------
// MFMA GEMM  C[M][N] = A[M][K] * BT[N][K]^T + bias(f32).  [validated r2-r4]
// ---------------------------------------------------------------------------
__global__ __launch_bounds__(256) void gemm_bt(const u16* __restrict__ A,
                                               const u16* __restrict__ BT,
                                               const float* __restrict__ bias,
                                               float* Cf, u16* Cb,
                                               int M, int N, int K) {
  __shared__ u16 lA[128 * 64];
  __shared__ u16 lB[128 * 64];
  const int t = threadIdx.x;
  const int lane = t & 63, w = t >> 6;
  const int g = lane >> 4, l16 = lane & 15;
  const int wr = w >> 1, wc = w & 1;
  const u16* Ab = A + (size_t)blockIdx.x * 128 * K;
  const u16* Bb = BT + (size_t)blockIdx.y * 128 * K;

  f32x4 acc[4][4];
#pragma unroll
  for (int mi = 0; mi < 4; ++mi)
#pragma unroll
    for (int ni = 0; ni < 4; ++ni) acc[mi][ni] = (f32x4)(0.0f);

  for (int k0 = 0; k0 < K; k0 += 64) {
    __syncthreads();
#pragma unroll
    for (int i = 0; i < 4; ++i) {
      int e = t * 8 + i * 2048;
      int row = e >> 6;
      int col16 = (e & 63) >> 3;
      int scol = (col16 ^ (row & 7)) * 8;
      gload_lds16(Ab + (size_t)row * K + k0 + scol, &lA[e]);
      gload_lds16(Bb + (size_t)row * K + k0 + scol, &lB[e]);
    }
    __syncthreads();
#pragma unroll
    for (int kk = 0; kk < 2; ++kk) {
      bf16x8 af[4], bfr[4];
#pragma unroll
      for (int mi = 0; mi < 4; ++mi) {
        int row = wr * 64 + mi * 16 + l16;
        af[mi] = *(const bf16x8*)&lA[row * 64 + (((4 * kk + g) ^ (l16 & 7)) << 3)];
      }
#pragma unroll
      for (int ni = 0; ni < 4; ++ni) {
        int row = wc * 64 + ni * 16 + l16;
        bfr[ni] = *(const bf16x8*)&lB[row * 64 + (((4 * kk + g) ^ (l16 & 7)) << 3)];
      }
#pragma unroll
      for (int mi = 0; mi < 4; ++mi)
#pragma unroll
        for (int ni = 0; ni < 4; ++ni)
          acc[mi][ni] = __builtin_amdgcn_mfma_f32_16x16x32_bf16(af[mi], bfr[ni],
                                                                acc[mi][ni], 0, 0, 0);
    }
  }

#pragma unroll
  for (int ni = 0; ni < 4; ++ni) {
    int n = blockIdx.y * 128 + wc * 64 + ni * 16 + l16;
    float bv = bias[n];
#pragma unroll
    for (int mi = 0; mi < 4; ++mi) {
      int m = blockIdx.x * 128 + wr * 64 + mi * 16 + 4 * g;
#pragma unroll
      for (int r = 0; r < 4; ++r) {
        float v = acc[mi][ni][r] + bv;
        if (Cf) Cf[(size_t)(m + r) * N + n] = v;
        else    Cb[(size_t)(m + r) * N + n] = f2bf(v);
      }
    }
  }
}

// ---------------------------------------------------------------------------
// Per-token RMSNorm(q,k) + interleaved RoPE + head-major relayout.
// [validated r2-r4]
// ---------------------------------------------------------------------------
__global__ __launch_bounds__(256) void rms_rope(const u16* __restrict__ qkv,
                                                const float* __restrict__ fcos,
                                                const float* __restrict__ fsin,
                                                const float* __restrict__ wq,
                                                const float* __restrict__ wk,
                                                u16* __restrict__ Qr,
                                                u16* __restrict__ Kr) {
  const int s = blockIdx.x;
  const int t = threadIdx.x;
  const int lane = t & 63, w = t >> 6;
  __shared__ float red[2][4];
  const u16* row = qkv + (size_t)s * (3 * HIDN);

  u16x8 xq = *(const u16x8*)&row[t * 8];
  u16x8 xk = *(const u16x8*)&row[HIDN + t * 8];
  float fq[8], fk[8];
  float ssq = 0.f, ssk = 0.f;
#pragma unroll
  for (int j = 0; j < 8; ++j) {
    fq[j] = bf2f(xq[j]); ssq += fq[j] * fq[j];
    fk[j] = bf2f(xk[j]); ssk += fk[j] * fk[j];
  }
#pragma unroll
  for (int off = 32; off >= 1; off >>= 1) {
    ssq += __shfl_xor(ssq, off);
    ssk += __shfl_xor(ssk, off);
  }
  if (lane == 0) { red[0][w] = ssq; red[1][w] = ssk; }
  __syncthreads();
  float sq = red[0][0] + red[0][1] + red[0][2] + red[0][3];
  float sk = red[1][0] + red[1][1] + red[1][2] + red[1][3];
  float rq = rsqrtf(sq / (float)HIDN + 1e-6f);
  float rk = rsqrtf(sk / (float)HIDN + 1e-6f);

  f32x4 wq0 = *(const f32x4*)&wq[t * 8];
  f32x4 wq1 = *(const f32x4*)&wq[t * 8 + 4];
  f32x4 wk0 = *(const f32x4*)&wk[t * 8];
  f32x4 wk1 = *(const f32x4*)&wk[t * 8 + 4];
  float wqa[8] = {wq0[0], wq0[1], wq0[2], wq0[3], wq1[0], wq1[1], wq1[2], wq1[3]};
  float wka[8] = {wk0[0], wk0[1], wk0[2], wk0[3], wk1[0], wk1[1], wk1[2], wk1[3]};
  const int c0 = t * 8;
  const int h = c0 >> 7;
  const int d0 = c0 & 127;
  const int i0 = d0 >> 1;
  const float* cp = fcos + (size_t)s * (DHD / 2) + i0;
  const float* sp = fsin + (size_t)s * (DHD / 2) + i0;
  const float qscale = 0.08838834764831845f;  // 1/sqrt(128)

  u16x8 oq, ok;
#pragma unroll
  for (int p = 0; p < 4; ++p) {
    float c = cp[p], sn = sp[p];
    float q1 = fq[2 * p] * rq * wqa[2 * p];
    float q2 = fq[2 * p + 1] * rq * wqa[2 * p + 1];
    float k1 = fk[2 * p] * rk * wka[2 * p];
    float k2 = fk[2 * p + 1] * rk * wka[2 * p + 1];
    oq[2 * p]     = f2bf((q1 * c - q2 * sn) * qscale);
    oq[2 * p + 1] = f2bf((q1 * sn + q2 * c) * qscale);
    ok[2 * p]     = f2bf(k1 * c - k2 * sn);
    ok[2 * p + 1] = f2bf(k1 * sn + k2 * c);
  }
  size_t o = (size_t)h * SLEN * DHD + (size_t)s * DHD + d0;
  *(u16x8*)&Qr[o] = oq;
  *(u16x8*)&Kr[o] = ok;
}

// ---------------------------------------------------------------------------
// MFMA flash attention v2: LDS-staged K/V (global_load_lds w16, XOR-swizzled,
// double-buffered, shared by 4 waves) + XCD-aware block mapping.
// 1-D grid of 512 blocks: xcd = lin&7 handles heads {xcd, xcd+8} only.
// Per block: 64 q-rows (4 waves x 16), KVBLK=64.
// ---------------------------------------------------------------------------
__global__ __launch_bounds__(256) void attn_fwd(const u16* __restrict__ Qr,
                                                const u16* __restrict__ Kr,
                                                const u16* __restrict__ Vt,
                                                u16* __restrict__ out) {
  const int lin = blockIdx.x;
  const int xcd = lin & 7, idx = lin >> 3;
  const int h = xcd + ((idx >> 5) << 3);   // heads xcd, xcd+8 on this XCD
  const int qb = idx & 31;
  const int t = threadIdx.x;
  const int lane = t & 63, w = t >> 6;
  const int g = lane >> 4, l16 = lane & 15;
  const int q0 = qb * 64 + w * 16;
  const u16* Qh = Qr + (size_t)h * SLEN * DHD;
  const u16* Kh = Kr + (size_t)h * SLEN * DHD;
  const u16* Vh = Vt + (size_t)h * DHD * SLEN;

  __shared__ u16 Kl[2][64 * 128];   // [kvrow][d], chunk16 XOR-swizzled by row&7
  __shared__ u16 Vl[2][128 * 64];   // [d][kv],   chunk16 XOR-swizzled by row&7
  __shared__ u16 Pl[4][16][72];

  bf16x8 aq[4];
#pragma unroll
  for (int dk = 0; dk < 4; ++dk)
    aq[dk] = *(const bf16x8*)&Qh[(size_t)(q0 + l16) * DHD + dk * 32 + g * 8];

  f32x4 o[8];
#pragma unroll
  for (int df = 0; df < 8; ++df) o[df] = (f32x4)(0.0f);
  float m[4], lsum[4];
#pragma unroll
  for (int r = 0; r < 4; ++r) { m[r] = -INFINITY; lsum[r] = 0.f; }

  // prologue: stage tile 0 into buffer 0
#pragma unroll
  for (int i = 0; i < 4; ++i) {
    int e = t * 8 + i * 2048;
    int kr = e >> 7, kc = (e & 127) >> 3;
    gload_lds16(Kh + (size_t)kr * DHD + ((kc ^ (kr & 7)) << 3), &Kl[0][e]);
    int vr = e >> 6, vc = (e & 63) >> 3;
    gload_lds16(Vh + (size_t)vr * SLEN + ((vc ^ (vr & 7)) << 3), &Vl[0][e]);
  }
  __syncthreads();

  int cur = 0;
  for (int kt = 0; kt < SLEN / 64; ++kt) {
    // stage next tile into the other buffer (overlaps compute below)
    if (kt + 1 < SLEN / 64) {
      const int kv1 = (kt + 1) * 64;
#pragma unroll
      for (int i = 0; i < 4; ++i) {
        int e = t * 8 + i * 2048;
        int kr = e >> 7, kc = (e & 127) >> 3;
        gload_lds16(Kh + (size_t)(kv1 + kr) * DHD + ((kc ^ (kr & 7)) << 3),
                    &Kl[cur ^ 1][e]);
        int vr = e >> 6, vc = (e & 63) >> 3;
        gload_lds16(Vh + (size_t)vr * SLEN + kv1 + ((vc ^ (vr & 7)) << 3),
                    &Vl[cur ^ 1][e]);
      }
    }

    // QK^T from swizzled K_lds
    f32x4 s4[4];
#pragma unroll
    for (int nf = 0; nf < 4; ++nf) s4[nf] = (f32x4)(0.0f);
#pragma unroll
    for (int nf = 0; nf < 4; ++nf) {
#pragma unroll
      for (int dk = 0; dk < 4; ++dk) {
        bf16x8 bk = *(const bf16x8*)&Kl[cur][(nf * 16 + l16) * 128 +
                                            (((dk * 4 + g) ^ (l16 & 7)) << 3)];
        s4[nf] = __builtin_amdgcn_mfma_f32_16x16x32_bf16(aq[dk], bk, s4[nf], 0, 0, 0);
      }
    }
    // online softmax (wave-parallel, 16-lane groups)
    float tm[4];
#pragma unroll
    for (int r = 0; r < 4; ++r) {
      tm[r] = s4[0][r];
#pragma unroll
      for (int nf = 1; nf < 4; ++nf) tm[r] = fmaxf(tm[r], s4[nf][r]);
    }
#pragma unroll
    for (int off = 1; off < 16; off <<= 1)
#pragma unroll
      for (int r = 0; r < 4; ++r) tm[r] = fmaxf(tm[r], __shfl_xor(tm[r], off));
    float corr[4], ts[4];
#pragma unroll
    for (int r = 0; r < 4; ++r) {
      float mn = fmaxf(m[r], tm[r]);
      corr[r] = __expf(m[r] - mn);
      m[r] = mn;
      ts[r] = 0.f;
    }
#pragma unroll
    for (int nf = 0; nf < 4; ++nf)
#pragma unroll
      for (int r = 0; r < 4; ++r) {
        float p = __expf(s4[nf][r] - m[r]);
        s4[nf][r] = p;
        ts[r] += p;
      }
#pragma unroll
    for (int off = 1; off < 16; off <<= 1)
#pragma unroll
      for (int r = 0; r < 4; ++r) ts[r] += __shfl_xor(ts[r], off);
#pragma unroll
    for (int r = 0; r < 4; ++r) lsum[r] = lsum[r] * corr[r] + ts[r];
#pragma unroll
    for (int df = 0; df < 8; ++df)
#pragma unroll
      for (int r = 0; r < 4; ++r) o[df][r] *= corr[r];
    // P -> wave-private LDS
#pragma unroll
    for (int nf = 0; nf < 4; ++nf)
#pragma unroll
      for (int r = 0; r < 4; ++r)
        Pl[w][4 * g + r][nf * 16 + l16] = f2bf(s4[nf][r]);
    // PV from swizzled V_lds
#pragma unroll
    for (int ks = 0; ks < 2; ++ks) {
      bf16x8 ap = *(const bf16x8*)&Pl[w][l16][ks * 32 + g * 8];
#pragma unroll
      for (int df = 0; df < 8; ++df) {
        bf16x8 bv = *(const bf16x8*)&Vl[cur][(df * 16 + l16) * 64 +
                                             (((ks * 4 + g) ^ (l16 & 7)) << 3)];
        o[df] = __builtin_amdgcn_mfma_f32_16x16x32_bf16(ap, bv, o[df], 0, 0, 0);
      }
    }
    __syncthreads();   // drains staging loads; protects both buffers
    cur ^= 1;
  }

  float inv[4];
#pragma unroll
  for (int r = 0; r < 4; ++r) inv[r] = 1.0f / lsum[r];
#pragma unroll
  for (int df = 0; df < 8; ++df)
#pragma unroll
    for (int r = 0; r < 4; ++r)
      out[(size_t)(q0 + 4 * g + r) * HIDN + h * DHD + df * 16 + l16] =
          f2bf(o[df][r] * inv[r]);
}

// ---------------------------------------------------------------------------
extern "C" void kernel_launch(void* const* d_in, const int* in_sizes, int n_in,
                              void* d_out, int out_size, void* d_ws, size_t ws_size,
                              hipStream_t stream) {
  (void)in_sizes; (void)n_in; (void)out_size; (void)ws_size;
  const float* hs   = (const float*)d_in[0];
  const float* fc   = (const float*)d_in[1];
  const float* fs   = (const float*)d_in[2];
  const float* wqkv = (const float*)d_in[3];
  const float* bqkv = (const float*)d_in[4];
  const float* wnq  = (const float*)d_in[5];
  const float* wnk  = (const float*)d_in[6];
  const float* wout = (const float*)d_in[7];
  const float* bout = (const float*)d_in[8];
  float* out = (float*)d_out;   // f32 output (r13 fix)
  char* ws = (char*)d_ws;

  u16* wqkvT = (u16*)(ws);                  // 6144x2048 bf16 (25,165,824 B)
  u16* woutT = (u16*)(ws + 25165824);       // 2048x2048 bf16 ( 8,388,608 B)
  u16* qkv   = (u16*)(ws + 33554432);       // 2048x6144 bf16 (25,165,824 B)
  u16* hsB   = (u16*)(ws + 58720256);       // 2048x2048 bf16
  u16* Qr    = (u16*)(ws + 58720256);       // alias hsB (dead after GEMM1)
  u16* Kr    = (u16*)(ws + 67108864);       // 16x2048x128 bf16
  u16* Vt    = (u16*)(ws + 75497472);       // 16x128x2048 bf16
  u16* attnO = (u16*)(ws + 83886080);       // 2048x2048 bf16 -> end 92,274,688

  // 1) weight transpose+convert, hidden convert (f32 -> bf16)
  transpcvt<<<dim3(32, 96), 256, 0, stream>>>(wqkv, wqkvT, 6144, 2048);
  transpcvt<<<dim3(32, 32), 256, 0, stream>>>(wout, woutT, 2048, 2048);
  cvt_bf16<<<dim3(2048), 256, 0, stream>>>(hs, hsB);
  // 2) QKV GEMM (MFMA)
  gemm_bt<<<dim3(16, 48), 256, 0, stream>>>(hsB, wqkvT, bqkv, nullptr, qkv,
                                            2048, 6144, 2048);
  // 3) RMSNorm + RoPE + head-major relayout (Q pre-scaled 1/sqrt(D))
  rms_rope<<<dim3(2048), 256, 0, stream>>>(qkv, fc, fs, wnq, wnk, Qr, Kr);
  // 4) V transpose -> Vt[h][d][s]
  transp<<<dim3(32, 2, 16), 256, 0, stream>>>(qkv + 4096, Vt, 6144, 2048, 128, 262144);
  // 5) MFMA flash attention v2 (LDS-staged, dbuf, XCD-aware)
  attn_fwd<<<dim3(512), 256, 0, stream>>>(Qr, Kr, Vt, attnO);
  // 6) output projection -> d_out (f32)
  gemm_bt<<<dim3(16, 16), 256, 0, stream>>>(attnO, woutT, bout, out, nullptr,
                                            2048, 2048, 2048);
}

// Round 16
// 214.224 us; speedup vs baseline: 50.3973x; 1.0715x over previous
//
#include <hip/hip_runtime.h>
#include <math.h>

typedef unsigned short u16;
typedef __bf16 bf16x8 __attribute__((ext_vector_type(8)));
typedef float f32x4 __attribute__((ext_vector_type(4)));
typedef unsigned short u16x8 __attribute__((ext_vector_type(8)));

#define SLEN 2048
#define HIDN 2048
#define NH   16
#define DHD  128

static __device__ __forceinline__ float bf2f(u16 u) {
  unsigned int i = ((unsigned int)u) << 16;
  return __builtin_bit_cast(float, i);
}
static __device__ __forceinline__ u16 f2bf(float f) {
  unsigned int x = __builtin_bit_cast(unsigned int, f);
  unsigned int r = x + 0x7fffu + ((x >> 16) & 1u);
  return (u16)(r >> 16);
}
static __device__ __forceinline__ void gload_lds16(const u16* g, u16* l) {
  __builtin_amdgcn_global_load_lds((const __attribute__((address_space(1))) void*)g,
                                   (__attribute__((address_space(3))) void*)l,
                                   16, 0, 0);
}

// ---------------------------------------------------------------------------
// Transpose + convert f32 -> bf16:  out[c][r] = (bf16)in[r][c].  64x64 tiles.
// ---------------------------------------------------------------------------
__global__ __launch_bounds__(256) void transpcvt(const float* __restrict__ in,
                                                 u16* __restrict__ out,
                                                 int istride, int ostride) {
  __shared__ float tl[64][65];
  const int t = threadIdx.x;
  const int r0 = blockIdx.x * 64, c0 = blockIdx.y * 64;
#pragma unroll
  for (int it = 0; it < 4; ++it) {
    int row = it * 16 + (t >> 4);
    int col = (t & 15) * 4;
    f32x4 v = *(const f32x4*)&in[(size_t)(r0 + row) * istride + c0 + col];
    tl[row][col] = v[0]; tl[row][col + 1] = v[1];
    tl[row][col + 2] = v[2]; tl[row][col + 3] = v[3];
  }
  __syncthreads();
#pragma unroll
  for (int it = 0; it < 2; ++it) {
    int orow = it * 32 + (t >> 3);
    int ocol = (t & 7) * 8;
    u16x8 v;
#pragma unroll
    for (int j = 0; j < 8; ++j) v[j] = f2bf(tl[ocol + j][orow]);
    *(u16x8*)&out[(size_t)(c0 + orow) * ostride + r0 + ocol] = v;
  }
}

// ---------------------------------------------------------------------------
// Elementwise f32 -> bf16 convert.
// ---------------------------------------------------------------------------
__global__ __launch_bounds__(256) void cvt_bf16(const float* __restrict__ in,
                                                u16* __restrict__ out) {
  int i = (blockIdx.x * 256 + threadIdx.x) * 8;
  f32x4 a = *(const f32x4*)&in[i];
  f32x4 b = *(const f32x4*)&in[i + 4];
  u16x8 v;
#pragma unroll
  for (int j = 0; j < 4; ++j) { v[j] = f2bf(a[j]); v[4 + j] = f2bf(b[j]); }
  *(u16x8*)&out[i] = v;
}

// ---------------------------------------------------------------------------
// bf16 tile transpose: out[c][r] = in[r][c].  64x64 tiles, grid (R/64,C/64,Z).
// ---------------------------------------------------------------------------
__global__ __launch_bounds__(256) void transp(const u16* __restrict__ in,
                                              u16* __restrict__ out,
                                              int istride, int ostride,
                                              int in_z, int out_z) {
  in  += (size_t)blockIdx.z * in_z;
  out += (size_t)blockIdx.z * out_z;
  __shared__ u16 tl[64][72];
  const int t  = threadIdx.x;
  const int r0 = blockIdx.x * 64, c0 = blockIdx.y * 64;
#pragma unroll
  for (int it = 0; it < 2; ++it) {
    int row = it * 32 + (t >> 3);
    int col = (t & 7) * 8;
    *(u16x8*)&tl[row][col] =
        *(const u16x8*)&in[(size_t)(r0 + row) * istride + c0 + col];
  }
  __syncthreads();
#pragma unroll
  for (int it = 0; it < 2; ++it) {
    int orow = it * 32 + (t >> 3);
    int ocol = (t & 7) * 8;
    u16x8 v;
#pragma unroll
    for (int j = 0; j < 8; ++j) v[j] = tl[ocol + j][orow];
    *(u16x8*)&out[(size_t)(c0 + orow) * ostride + r0 + ocol] = v;
  }
}

// ---------------------------------------------------------------------------
// MFMA GEMM  C[M][N] = A[M][K] * BT[N][K]^T + bias(f32).  [validated r2-r4]
// ---------------------------------------------------------------------------
__global__ __launch_bounds__(256) void gemm_bt(const u16* __restrict__ A,
                                               const u16* __restrict__ BT,
                                               const float* __restrict__ bias,
                                               float* Cf, u16* Cb,
                                               int M, int N, int K) {
  __shared__ u16 lA[128 * 64];
  __shared__ u16 lB[128 * 64];
  const int t = threadIdx.x;
  const int lane = t & 63, w = t >> 6;
  const int g = lane >> 4, l16 = lane & 15;
  const int wr = w >> 1, wc = w & 1;
  const u16* Ab = A + (size_t)blockIdx.x * 128 * K;
  const u16* Bb = BT + (size_t)blockIdx.y * 128 * K;

  f32x4 acc[4][4];
#pragma unroll
  for (int mi = 0; mi < 4; ++mi)
#pragma unroll
    for (int ni = 0; ni < 4; ++ni) acc[mi][ni] = (f32x4)(0.0f);

  for (int k0 = 0; k0 < K; k0 += 64) {
    __syncthreads();
#pragma unroll
    for (int i = 0; i < 4; ++i) {
      int e = t * 8 + i * 2048;
      int row = e >> 6;
      int col16 = (e & 63) >> 3;
      int scol = (col16 ^ (row & 7)) * 8;
      gload_lds16(Ab + (size_t)row * K + k0 + scol, &lA[e]);
      gload_lds16(Bb + (size_t)row * K + k0 + scol, &lB[e]);
    }
    __syncthreads();
#pragma unroll
    for (int kk = 0; kk < 2; ++kk) {
      bf16x8 af[4], bfr[4];
#pragma unroll
      for (int mi = 0; mi < 4; ++mi) {
        int row = wr * 64 + mi * 16 + l16;
        af[mi] = *(const bf16x8*)&lA[row * 64 + (((4 * kk + g) ^ (l16 & 7)) << 3)];
      }
#pragma unroll
      for (int ni = 0; ni < 4; ++ni) {
        int row = wc * 64 + ni * 16 + l16;
        bfr[ni] = *(const bf16x8*)&lB[row * 64 + (((4 * kk + g) ^ (l16 & 7)) << 3)];
      }
#pragma unroll
      for (int mi = 0; mi < 4; ++mi)
#pragma unroll
        for (int ni = 0; ni < 4; ++ni)
          acc[mi][ni] = __builtin_amdgcn_mfma_f32_16x16x32_bf16(af[mi], bfr[ni],
                                                                acc[mi][ni], 0, 0, 0);
    }
  }

#pragma unroll
  for (int ni = 0; ni < 4; ++ni) {
    int n = blockIdx.y * 128 + wc * 64 + ni * 16 + l16;
    float bv = bias[n];
#pragma unroll
    for (int mi = 0; mi < 4; ++mi) {
      int m = blockIdx.x * 128 + wr * 64 + mi * 16 + 4 * g;
#pragma unroll
      for (int r = 0; r < 4; ++r) {
        float v = acc[mi][ni][r] + bv;
        if (Cf) Cf[(size_t)(m + r) * N + n] = v;
        else    Cb[(size_t)(m + r) * N + n] = f2bf(v);
      }
    }
  }
}

// ---------------------------------------------------------------------------
// Per-token RMSNorm(q,k) + interleaved RoPE + head-major relayout.
// Q pre-scaled by log2(e)/sqrt(D) -> attention softmax runs in exp2 domain.
// ---------------------------------------------------------------------------
__global__ __launch_bounds__(256) void rms_rope(const u16* __restrict__ qkv,
                                                const float* __restrict__ fcos,
                                                const float* __restrict__ fsin,
                                                const float* __restrict__ wq,
                                                const float* __restrict__ wk,
                                                u16* __restrict__ Qr,
                                                u16* __restrict__ Kr) {
  const int s = blockIdx.x;
  const int t = threadIdx.x;
  const int lane = t & 63, w = t >> 6;
  __shared__ float red[2][4];
  const u16* row = qkv + (size_t)s * (3 * HIDN);

  u16x8 xq = *(const u16x8*)&row[t * 8];
  u16x8 xk = *(const u16x8*)&row[HIDN + t * 8];
  float fq[8], fk[8];
  float ssq = 0.f, ssk = 0.f;
#pragma unroll
  for (int j = 0; j < 8; ++j) {
    fq[j] = bf2f(xq[j]); ssq += fq[j] * fq[j];
    fk[j] = bf2f(xk[j]); ssk += fk[j] * fk[j];
  }
#pragma unroll
  for (int off = 32; off >= 1; off >>= 1) {
    ssq += __shfl_xor(ssq, off);
    ssk += __shfl_xor(ssk, off);
  }
  if (lane == 0) { red[0][w] = ssq; red[1][w] = ssk; }
  __syncthreads();
  float sq = red[0][0] + red[0][1] + red[0][2] + red[0][3];
  float sk = red[1][0] + red[1][1] + red[1][2] + red[1][3];
  float rq = rsqrtf(sq / (float)HIDN + 1e-6f);
  float rk = rsqrtf(sk / (float)HIDN + 1e-6f);

  f32x4 wq0 = *(const f32x4*)&wq[t * 8];
  f32x4 wq1 = *(const f32x4*)&wq[t * 8 + 4];
  f32x4 wk0 = *(const f32x4*)&wk[t * 8];
  f32x4 wk1 = *(const f32x4*)&wk[t * 8 + 4];
  float wqa[8] = {wq0[0], wq0[1], wq0[2], wq0[3], wq1[0], wq1[1], wq1[2], wq1[3]};
  float wka[8] = {wk0[0], wk0[1], wk0[2], wk0[3], wk1[0], wk1[1], wk1[2], wk1[3]};
  const int c0 = t * 8;
  const int h = c0 >> 7;
  const int d0 = c0 & 127;
  const int i0 = d0 >> 1;
  const float* cp = fcos + (size_t)s * (DHD / 2) + i0;
  const float* sp = fsin + (size_t)s * (DHD / 2) + i0;
  const float qscale = 0.12751744925f;  // log2(e)/sqrt(128)

  u16x8 oq, ok;
#pragma unroll
  for (int p = 0; p < 4; ++p) {
    float c = cp[p], sn = sp[p];
    float q1 = fq[2 * p] * rq * wqa[2 * p];
    float q2 = fq[2 * p + 1] * rq * wqa[2 * p + 1];
    float k1 = fk[2 * p] * rk * wka[2 * p];
    float k2 = fk[2 * p + 1] * rk * wka[2 * p + 1];
    oq[2 * p]     = f2bf((q1 * c - q2 * sn) * qscale);
    oq[2 * p + 1] = f2bf((q1 * sn + q2 * c) * qscale);
    ok[2 * p]     = f2bf(k1 * c - k2 * sn);
    ok[2 * p + 1] = f2bf(k1 * sn + k2 * c);
  }
  size_t o = (size_t)h * SLEN * DHD + (size_t)s * DHD + d0;
  *(u16x8*)&Qr[o] = oq;
  *(u16x8*)&Kr[o] = ok;
}

// ---------------------------------------------------------------------------
// MFMA flash attention v3: swapped-operand QK^T -> lane-local softmax.
// mfma(K_frag, Q_frag) gives scores [kv=nf*16+4g+r][q=l16]: each lane holds 16
// scores of ONE q-row.  Softmax: 15 local fmax + 2 shfl_xor (group-of-4
// reduce), local exp2, local sum + 2 shfl_xor.  corr/inv broadcast to the PV
// accumulator rows (q=4g+r) via 4 shfl from owner lanes (src=20g+r).
// Exact rescale-skip via __all(tm<=m).  LDS staging/XCD map from v2 unchanged.
// ---------------------------------------------------------------------------
__global__ __launch_bounds__(256) void attn_fwd(const u16* __restrict__ Qr,
                                                const u16* __restrict__ Kr,
                                                const u16* __restrict__ Vt,
                                                u16* __restrict__ out) {
  const int lin = blockIdx.x;
  const int xcd = lin & 7, idx = lin >> 3;
  const int h = xcd + ((idx >> 5) << 3);
  const int qb = idx & 31;
  const int t = threadIdx.x;
  const int lane = t & 63, w = t >> 6;
  const int g = lane >> 4, l16 = lane & 15;
  const int q0 = qb * 64 + w * 16;
  const u16* Qh = Qr + (size_t)h * SLEN * DHD;
  const u16* Kh = Kr + (size_t)h * SLEN * DHD;
  const u16* Vh = Vt + (size_t)h * DHD * SLEN;

  __shared__ u16 Kl[2][64 * 128];
  __shared__ u16 Vl[2][128 * 64];
  __shared__ u16 Pl[4][16][72];

  bf16x8 aq[4];
#pragma unroll
  for (int dk = 0; dk < 4; ++dk)
    aq[dk] = *(const bf16x8*)&Qh[(size_t)(q0 + l16) * DHD + dk * 32 + g * 8];

  f32x4 o[8];
#pragma unroll
  for (int df = 0; df < 8; ++df) o[df] = (f32x4)(0.0f);
  float m = -INFINITY, lsum = 0.f;   // state for q = l16 (dup across g)

#pragma unroll
  for (int i = 0; i < 4; ++i) {
    int e = t * 8 + i * 2048;
    int kr = e >> 7, kc = (e & 127) >> 3;
    gload_lds16(Kh + (size_t)kr * DHD + ((kc ^ (kr & 7)) << 3), &Kl[0][e]);
    int vr = e >> 6, vc = (e & 63) >> 3;
    gload_lds16(Vh + (size_t)vr * SLEN + ((vc ^ (vr & 7)) << 3), &Vl[0][e]);
  }
  __syncthreads();

  int cur = 0;
  for (int kt = 0; kt < SLEN / 64; ++kt) {
    if (kt + 1 < SLEN / 64) {
      const int kv1 = (kt + 1) * 64;
#pragma unroll
      for (int i = 0; i < 4; ++i) {
        int e = t * 8 + i * 2048;
        int kr = e >> 7, kc = (e & 127) >> 3;
        gload_lds16(Kh + (size_t)(kv1 + kr) * DHD + ((kc ^ (kr & 7)) << 3),
                    &Kl[cur ^ 1][e]);
        int vr = e >> 6, vc = (e & 63) >> 3;
        gload_lds16(Vh + (size_t)vr * SLEN + kv1 + ((vc ^ (vr & 7)) << 3),
                    &Vl[cur ^ 1][e]);
      }
    }

    // QK^T, SWAPPED operands: s4[nf] reg r = score[kv=nf*16+4g+r][q=l16]
    f32x4 s4[4];
#pragma unroll
    for (int nf = 0; nf < 4; ++nf) s4[nf] = (f32x4)(0.0f);
#pragma unroll
    for (int nf = 0; nf < 4; ++nf) {
#pragma unroll
      for (int dk = 0; dk < 4; ++dk) {
        bf16x8 bk = *(const bf16x8*)&Kl[cur][(nf * 16 + l16) * 128 +
                                            (((dk * 4 + g) ^ (l16 & 7)) << 3)];
        s4[nf] = __builtin_amdgcn_mfma_f32_16x16x32_bf16(bk, aq[dk], s4[nf], 0, 0, 0);
      }
    }
    // lane-local softmax (scores in log2 domain)
    float tm = s4[0][0];
#pragma unroll
    for (int nf = 0; nf < 4; ++nf)
#pragma unroll
      for (int r = 0; r < 4; ++r) tm = fmaxf(tm, s4[nf][r]);
    tm = fmaxf(tm, __shfl_xor(tm, 16));
    tm = fmaxf(tm, __shfl_xor(tm, 32));
    const bool nogrow = (tm <= m);
    const float mn = nogrow ? m : tm;
    float ls = 0.f;
#pragma unroll
    for (int nf = 0; nf < 4; ++nf)
#pragma unroll
      for (int r = 0; r < 4; ++r) {
        float p = exp2f(s4[nf][r] - mn);
        s4[nf][r] = p;
        ls += p;
      }
    ls += __shfl_xor(ls, 16);
    ls += __shfl_xor(ls, 32);
    if (__all(nogrow)) {
      lsum += ls;
    } else {
      float corr = exp2f(m - mn);
      m = mn;
      lsum = lsum * corr + ls;
#pragma unroll
      for (int r = 0; r < 4; ++r) {
        float cr = __shfl(corr, 20 * g + r);   // owner lane g*16 + (4g+r)
#pragma unroll
        for (int df = 0; df < 8; ++df) o[df][r] *= cr;
      }
    }
    // P -> wave-private LDS, layout [q=l16][kv]
#pragma unroll
    for (int nf = 0; nf < 4; ++nf)
#pragma unroll
      for (int r = 0; r < 4; ++r)
        Pl[w][l16][nf * 16 + 4 * g + r] = f2bf(s4[nf][r]);
    // PV (unchanged)
#pragma unroll
    for (int ks = 0; ks < 2; ++ks) {
      bf16x8 ap = *(const bf16x8*)&Pl[w][l16][ks * 32 + g * 8];
#pragma unroll
      for (int df = 0; df < 8; ++df) {
        bf16x8 bv = *(const bf16x8*)&Vl[cur][(df * 16 + l16) * 64 +
                                             (((ks * 4 + g) ^ (l16 & 7)) << 3)];
        o[df] = __builtin_amdgcn_mfma_f32_16x16x32_bf16(ap, bv, o[df], 0, 0, 0);
      }
    }
    __syncthreads();
    cur ^= 1;
  }

  const float invq = 1.0f / lsum;   // for q = l16
#pragma unroll
  for (int r = 0; r < 4; ++r) {
    float ir = __shfl(invq, 20 * g + r);
#pragma unroll
    for (int df = 0; df < 8; ++df)
      out[(size_t)(q0 + 4 * g + r) * HIDN + h * DHD + df * 16 + l16] =
          f2bf(o[df][r] * ir);
  }
}

// ---------------------------------------------------------------------------
extern "C" void kernel_launch(void* const* d_in, const int* in_sizes, int n_in,
                              void* d_out, int out_size, void* d_ws, size_t ws_size,
                              hipStream_t stream) {
  (void)in_sizes; (void)n_in; (void)out_size; (void)ws_size;
  const float* hs   = (const float*)d_in[0];
  const float* fc   = (const float*)d_in[1];
  const float* fs   = (const float*)d_in[2];
  const float* wqkv = (const float*)d_in[3];
  const float* bqkv = (const float*)d_in[4];
  const float* wnq  = (const float*)d_in[5];
  const float* wnk  = (const float*)d_in[6];
  const float* wout = (const float*)d_in[7];
  const float* bout = (const float*)d_in[8];
  float* out = (float*)d_out;
  char* ws = (char*)d_ws;

  u16* wqkvT = (u16*)(ws);                  // 6144x2048 bf16 (25,165,824 B)
  u16* woutT = (u16*)(ws + 25165824);       // 2048x2048 bf16 ( 8,388,608 B)
  u16* qkv   = (u16*)(ws + 33554432);       // 2048x6144 bf16 (25,165,824 B)
  u16* hsB   = (u16*)(ws + 58720256);       // 2048x2048 bf16
  u16* Qr    = (u16*)(ws + 58720256);       // alias hsB (dead after GEMM1)
  u16* Kr    = (u16*)(ws + 67108864);       // 16x2048x128 bf16
  u16* Vt    = (u16*)(ws + 75497472);       // 16x128x2048 bf16
  u16* attnO = (u16*)(ws + 83886080);       // 2048x2048 bf16

  transpcvt<<<dim3(32, 96), 256, 0, stream>>>(wqkv, wqkvT, 6144, 2048);
  transpcvt<<<dim3(32, 32), 256, 0, stream>>>(wout, woutT, 2048, 2048);
  cvt_bf16<<<dim3(2048), 256, 0, stream>>>(hs, hsB);
  gemm_bt<<<dim3(16, 48), 256, 0, stream>>>(hsB, wqkvT, bqkv, nullptr, qkv,
                                            2048, 6144, 2048);
  rms_rope<<<dim3(2048), 256, 0, stream>>>(qkv, fc, fs, wnq, wnk, Qr, Kr);
  transp<<<dim3(32, 2, 16), 256, 0, stream>>>(qkv + 4096, Vt, 6144, 2048, 128, 262144);
  attn_fwd<<<dim3(512), 256, 0, stream>>>(Qr, Kr, Vt, attnO);
  gemm_bt<<<dim3(16, 16), 256, 0, stream>>>(attnO, woutT, bout, out, nullptr,
                                            2048, 2048, 2048);
}